// Round 15
// baseline (143.008 us; speedup 1.0000x reference)
//
#include <hip/hip_runtime.h>
#include <hip/hip_bf16.h>

// sLSTM cell: B=8192, I=1024, H=1024.
// G = [x|h] @ [W|R]^T  (M=8192, N=4096=4 gates x 1024, K=2048), then elementwise.
// Round 15: r14 (validated, 129.9us) + ONE lever: A-staging global_load_lds
// marked non-temporal (aux=2, gfx950 CPol NT). Theory: A's 16x-amplified
// stream flows through L2 and evicts the XCD's 2MB B panels, forcing B
// re-stages to L3 (512MB L3 demand ~ 51us > 41us skeleton). NT on A keeps B
// L2-resident -> L3 demand halves. B staging unchanged (aux=0). Cache policy
// cannot affect correctness; math byte-identical to r14.

#define B_SZ 8192
#define K_SZ 2048
#define H_SZ 1024
#define OUTSTRIDE 8388608   // B_SZ*H_SZ
#define EPSF 1e-7f
#define NT 32               // K_SZ / 64 (full-K trip count)
#define ATILE 16384         // ushorts per A K-tile buffer (256 rows x 64 k)
#define BTILE 16384
#define FLAG_OFF (48u * 1024u * 1024u)   // flags location in d_ws (bytes)

using bf16x8 = __attribute__((ext_vector_type(8))) short;
using f32x4  = __attribute__((ext_vector_type(4))) float;

__device__ inline ushort f2bf(float f) {
    uint u = __float_as_uint(f);
    u = (u + 0x7fffu + ((u >> 16) & 1u)) >> 16;
    return (ushort)u;
}

#if __has_builtin(__builtin_amdgcn_rcpf)
__device__ inline float frcp(float x) { return __builtin_amdgcn_rcpf(x); }
#else
__device__ inline float frcp(float x) { return 1.0f / x; }
#endif
__device__ inline float fsigmoid(float x) { return frcp(1.0f + __expf(-x)); }
__device__ inline float ftanh(float x) {
    return 1.0f - 2.0f * frcp(__expf(2.0f * x) + 1.0f);
}

// aux=0: default policy (B panels; want L2 residency)
#define GLOAD16(gp, lp)                                                              \
    __builtin_amdgcn_global_load_lds((const __attribute__((address_space(1))) void*)(gp), \
                                     (__attribute__((address_space(3))) void*)(lp),  \
                                     16, 0, 0)
// aux=2: NT (A stream; don't claim L2 capacity)
#define GLOAD16NT(gp, lp)                                                            \
    __builtin_amdgcn_global_load_lds((const __attribute__((address_space(1))) void*)(gp), \
                                     (__attribute__((address_space(3))) void*)(lp),  \
                                     16, 0, 2)

#define BAR() do { asm volatile("" ::: "memory"); __builtin_amdgcn_s_barrier(); \
                   asm volatile("" ::: "memory"); } while (0)
#define WAITVM(n) asm volatile("s_waitcnt vmcnt(" #n ")" ::: "memory")

// pack one 8-float chunk -> 8 bf16 (uint4)
__device__ inline void pack_chunk(const float* __restrict__ src, ushort* __restrict__ dst) {
    float4 v0 = ((const float4*)src)[0];
    float4 v1 = ((const float4*)src)[1];
    uint4 o;
    o.x = (uint)f2bf(v0.x) | ((uint)f2bf(v0.y) << 16);
    o.y = (uint)f2bf(v0.z) | ((uint)f2bf(v0.w) << 16);
    o.z = (uint)f2bf(v1.x) | ((uint)f2bf(v1.y) << 16);
    o.w = (uint)f2bf(v1.z) | ((uint)f2bf(v1.w) << 16);
    ((uint4*)dst)[0] = o;
}

// ---------------- consolidated prologue ----------------

__global__ __launch_bounds__(256)
void prologue_main(const float* __restrict__ x, const float* __restrict__ h,
                   const float* __restrict__ c, const float* __restrict__ n,
                   const float* __restrict__ m,
                   const float* __restrict__ w_i, const float* __restrict__ w_f,
                   const float* __restrict__ w_o, const float* __restrict__ w_z,
                   ushort* __restrict__ XH, ushort* __restrict__ Wp,
                   int* __restrict__ flags) {
    const int gid = blockIdx.x * 256 + threadIdx.x;   // [0, 524288)
    const int NTHR = 2048 * 256;

    // x-half pack: chunk j -> row j>>7, kc j&127 (2 iters/thread)
#pragma unroll
    for (int it = 0; it < 2; ++it) {
        const int j = gid + it * NTHR;
        const int b = j >> 7, kc = j & 127;
        pack_chunk(x + (size_t)b * 1024 + kc * 8, XH + (size_t)b * 2048 + kc * 8);
    }
    // W-half pack: 1 chunk/thread
    {
        const int nn = gid >> 7, kc = gid & 127;
        const int g = nn >> 10, hr = nn & 1023;
        const float* wsel = (g == 0) ? w_i : (g == 1) ? w_f : (g == 2) ? w_o : w_z;
        pack_chunk(wsel + (size_t)hr * 1024 + kc * 8, Wp + (size_t)nn * 2048 + kc * 8);
    }
    // detection (NT loads; these arrays are read-once before the fused kernel)
    if (flags) {
        const int NF4 = (B_SZ * H_SZ) / 4;   // 2097152
        const f32x4* h4 = (const f32x4*)h;
        const f32x4* c4 = (const f32x4*)c;
        const f32x4* n4 = (const f32x4*)n;
        const f32x4* m4 = (const f32x4*)m;
        bool nzh = false, nzc = false;
        for (int i = gid; i < NF4; i += NTHR) {
            f32x4 vh = __builtin_nontemporal_load(h4 + i);
            nzh |= (vh[0] != 0.f) | (vh[1] != 0.f) | (vh[2] != 0.f) | (vh[3] != 0.f);
            f32x4 vc = __builtin_nontemporal_load(c4 + i);
            f32x4 vn = __builtin_nontemporal_load(n4 + i);
            f32x4 vm = __builtin_nontemporal_load(m4 + i);
            nzc |= (vc[0] != 0.f) | (vc[1] != 0.f) | (vc[2] != 0.f) | (vc[3] != 0.f);
            nzc |= (vn[0] != 0.f) | (vn[1] != 0.f) | (vn[2] != 0.f) | (vn[3] != 0.f);
            nzc |= (vm[0] != 0.f) | (vm[1] != 0.f) | (vm[2] != 0.f) | (vm[3] != 0.f);
        }
        if (__ballot(nzh) != 0ull && (threadIdx.x & 63) == 0) atomicOr(flags, 1);
        if (__ballot(nzc) != 0ull && (threadIdx.x & 63) == 0) atomicOr(flags + 1, 1);
    }
}

// h-half of XH + R-half of Wp; skipped when h==0 (fused never reads k>=1024 at nt=16)
__global__ __launch_bounds__(256)
void pack_hr(const float* __restrict__ h,
             const float* __restrict__ r_i, const float* __restrict__ r_f,
             const float* __restrict__ r_o, const float* __restrict__ r_z,
             ushort* __restrict__ XH, ushort* __restrict__ Wp,
             const int* __restrict__ flags) {
    if (flags && flags[0] == 0) return;
    const int gid = blockIdx.x * 256 + threadIdx.x;   // [0, 1572864)
    if (gid < 1048576) {
        const int b = gid >> 7, kc = gid & 127;
        pack_chunk(h + (size_t)b * 1024 + kc * 8,
                   XH + (size_t)b * 2048 + 1024 + kc * 8);
    } else {
        const int j = gid - 1048576;
        const int nn = j >> 7, kc = j & 127;
        const int g = nn >> 10, hr = nn & 1023;
        const float* rsel = (g == 0) ? r_i : (g == 1) ? r_f : (g == 2) ? r_o : r_z;
        pack_chunk(rsel + (size_t)hr * 1024 + kc * 8,
                   Wp + (size_t)nn * 2048 + 1024 + kc * 8);
    }
}

// ---------------- fused GEMM + sLSTM epilogue (r14 body; A stages NT) ----------------

__global__ __launch_bounds__(512, 2)
void slstm_fused(const ushort* __restrict__ XH, const ushort* __restrict__ Wp,
                 const float* __restrict__ c_prev, const float* __restrict__ n_prev,
                 const float* __restrict__ m_prev,
                 const float* __restrict__ bi_, const float* __restrict__ bf_,
                 const float* __restrict__ bo_, const float* __restrict__ bz_,
                 const int* __restrict__ flags,
                 float* __restrict__ out) {
    __shared__ __align__(16) ushort Alds[3 * ATILE];   // 96 KB (triple)
    __shared__ __align__(16) ushort Blds[2 * BTILE];   // 64 KB (double)

    const int nt = (flags == nullptr) ? NT : (flags[0] ? NT : NT / 2);
    const bool cz = (flags != nullptr) && (flags[1] == 0);   // c/n/m all zero

    const int tid  = threadIdx.x;
    const int lane = tid & 63;
    const int wave = tid >> 6;
    const int wm = wave >> 2, wn = wave & 3;   // 2 x 4 waves
    const int l16 = lane & 15, lk = lane >> 4;

    // XCD-pairing swizzle
    const int wgid  = blockIdx.x;
    const int xcd   = wgid & 7;
    const int rr    = (wgid >> 3) & 31;
    const int rnd   = wgid >> 8;
    const int hcol  = (2 * xcd + (rr & 1)) * 64;
    const int brow  = (16 * rnd + (rr >> 1)) * 256;

    // per-lane pre-swizzled staging source pointers
    const ushort* srcA[4];
    const ushort* srcB[4];
#pragma unroll
    for (int c = 0; c < 4; ++c) {
        const int s = c * 512 + tid;          // linear 16B slot
        const int row = s >> 3, cph = s & 7;
        const int cl = cph ^ (row & 7);       // logical chunk
        srcA[c] = XH + (size_t)(brow + row) * 2048 + cl * 8;
        const int g = row >> 6, hh = row & 63;
        srcB[c] = Wp + (size_t)(g * 1024 + hcol + hh) * 2048 + cl * 8;
    }

    const int x7  = l16 & 7;
    const int cA0 = ((0 + lk) ^ x7) * 8;      // kh=0 phys chunk
    const int cA1 = ((4 + lk) ^ x7) * 8;      // kh=1 phys chunk
    const int abase = (wm * 128 + l16) * 64;
    const int bbase = (wn * 16 + l16) * 64;

    f32x4 acc[8][4];                          // [mf][gate]
#pragma unroll
    for (int m = 0; m < 8; ++m)
#pragma unroll
        for (int g = 0; g < 4; ++g)
            acc[m][g] = (f32x4){0.f, 0.f, 0.f, 0.f};

#define STAGE(LD, srcarr, ldsbase, tko)                                  \
    do {                                                                 \
        _Pragma("unroll")                                                \
        for (int c = 0; c < 4; ++c)                                      \
            LD(srcarr[c] + (tko), (ldsbase) + (c * 512 + wave * 64) * 8); \
    } while (0)

    const ushort* Acur = Alds;
    const ushort* Anext = Alds + ATILE;
    const ushort* Athird = Alds + 2 * ATILE;

    // prologue: B(0),A(0),B(1),A(1),A(2); WAITVM(12) retires B(0),A(0)
    STAGE(GLOAD16,   srcB, Blds, 0);
    STAGE(GLOAD16NT, srcA, (ushort*)Acur, 0);
    STAGE(GLOAD16,   srcB, Blds + BTILE, 64);
    STAGE(GLOAD16NT, srcA, (ushort*)Anext, 64);
    STAGE(GLOAD16NT, srcA, (ushort*)Athird, 128);
    WAITVM(12);
    BAR();

    bf16x8 a_lo[4][2], a_hi[4][2], b01[2][2], b23[2][2];

#pragma unroll
    for (int m = 0; m < 4; ++m) {
        a_lo[m][0] = *(const bf16x8*)(Acur + abase + m * 1024 + cA0);
        a_lo[m][1] = *(const bf16x8*)(Acur + abase + m * 1024 + cA1);
    }
#pragma unroll
    for (int g = 0; g < 2; ++g) {
        b01[g][0] = *(const bf16x8*)(Blds + bbase + g * 4096 + cA0);
        b01[g][1] = *(const bf16x8*)(Blds + bbase + g * 4096 + cA1);
    }

    for (int t = 0; t < nt; ++t) {
        const ushort* Bb = Blds + (t & 1) * BTILE;
        ushort* Bw = (ushort*)Bb;             // B(t+2) dest (same parity)
        ushort* Aw = (ushort*)Acur;           // A(t+3) dest = buf t%3
        const bool stB = (t < nt - 2);
        const bool stA = (t < nt - 3);

        // ---- P0: issue b23(t) reads; MFMA mf0-3 x g0-1 ----
#pragma unroll
        for (int g = 0; g < 2; ++g) {
            b23[g][0] = *(const bf16x8*)(Bb + bbase + (g + 2) * 4096 + cA0);
            b23[g][1] = *(const bf16x8*)(Bb + bbase + (g + 2) * 4096 + cA1);
        }
        __builtin_amdgcn_s_setprio(1);
#pragma unroll
        for (int m = 0; m < 4; ++m)
#pragma unroll
            for (int g = 0; g < 2; ++g) {
                acc[m][g] = __builtin_amdgcn_mfma_f32_16x16x32_bf16(a_lo[m][0], b01[g][0], acc[m][g], 0, 0, 0);
                acc[m][g] = __builtin_amdgcn_mfma_f32_16x16x32_bf16(a_lo[m][1], b01[g][1], acc[m][g], 0, 0, 0);
            }
        __builtin_amdgcn_s_setprio(0);

        // ---- P1: issue a_hi(t) reads; MFMA mf0-3 x g2-3; BAR_a ----
#pragma unroll
        for (int m = 0; m < 4; ++m) {
            a_hi[m][0] = *(const bf16x8*)(Acur + abase + (m + 4) * 1024 + cA0);
            a_hi[m][1] = *(const bf16x8*)(Acur + abase + (m + 4) * 1024 + cA1);
        }
        __builtin_amdgcn_s_setprio(1);
#pragma unroll
        for (int m = 0; m < 4; ++m)
#pragma unroll
            for (int g = 0; g < 2; ++g) {
                acc[m][g + 2] = __builtin_amdgcn_mfma_f32_16x16x32_bf16(a_lo[m][0], b23[g][0], acc[m][g + 2], 0, 0, 0);
                acc[m][g + 2] = __builtin_amdgcn_mfma_f32_16x16x32_bf16(a_lo[m][1], b23[g][1], acc[m][g + 2], 0, 0, 0);
            }
        __builtin_amdgcn_s_setprio(0);
        BAR();   // BAR_a: all B(t) reads complete -> B stage may begin

        // ---- P2: stage B(t+2); MFMA mf4-7 x g0-1; BAR_b ----
        if (stB) STAGE(GLOAD16, srcB, Bw, (t + 2) * 64);
        __builtin_amdgcn_s_setprio(1);
#pragma unroll
        for (int m = 0; m < 4; ++m)
#pragma unroll
            for (int g = 0; g < 2; ++g) {
                acc[m + 4][g] = __builtin_amdgcn_mfma_f32_16x16x32_bf16(a_hi[m][0], b01[g][0], acc[m + 4][g], 0, 0, 0);
                acc[m + 4][g] = __builtin_amdgcn_mfma_f32_16x16x32_bf16(a_hi[m][1], b01[g][1], acc[m + 4][g], 0, 0, 0);
            }
        __builtin_amdgcn_s_setprio(0);
        BAR();   // BAR_b: all A(t) reads complete -> A stage may begin

        // ---- P3: stage A(t+3); MFMA mf4-7 x g2-3; WAITVM; BAR_c ----
        if (stA) STAGE(GLOAD16NT, srcA, Aw, (t + 3) * 64);
        __builtin_amdgcn_s_setprio(1);
#pragma unroll
        for (int m = 0; m < 4; ++m)
#pragma unroll
            for (int g = 0; g < 2; ++g) {
                acc[m + 4][g + 2] = __builtin_amdgcn_mfma_f32_16x16x32_bf16(a_hi[m][0], b23[g][0], acc[m + 4][g + 2], 0, 0, 0);
                acc[m + 4][g + 2] = __builtin_amdgcn_mfma_f32_16x16x32_bf16(a_hi[m][1], b23[g][1], acc[m + 4][g + 2], 0, 0, 0);
            }
        __builtin_amdgcn_s_setprio(0);
        if (t < nt - 3) { WAITVM(12); } else { WAITVM(0); }
        BAR();   // BAR_c

        // ---- next-tile frag reads ----
        if (t < nt - 1) {
            const ushort* Bn = Blds + ((t + 1) & 1) * BTILE;
#pragma unroll
            for (int m = 0; m < 4; ++m) {
                a_lo[m][0] = *(const bf16x8*)(Anext + abase + m * 1024 + cA0);
                a_lo[m][1] = *(const bf16x8*)(Anext + abase + m * 1024 + cA1);
            }
#pragma unroll
            for (int g = 0; g < 2; ++g) {
                b01[g][0] = *(const bf16x8*)(Bn + bbase + g * 4096 + cA0);
                b01[g][1] = *(const bf16x8*)(Bn + bbase + g * 4096 + cA1);
            }
        }
        // rotate A buffers
        const ushort* tmp = Acur;
        Acur = Anext; Anext = Athird; Athird = tmp;
    }
#undef STAGE

    // ---- in-register sLSTM epilogue (fast-math, plain stores) ----
    const int h = hcol + wn * 16 + l16;
    const float vbi = bi_[h], vbf = bf_[h], vbo = bo_[h], vbz = bz_[h];

    if (cz) {
        // zero-state path: bit-identical to full path with c=n=m=0
#pragma unroll
        for (int mf = 0; mf < 8; ++mf) {
#pragma unroll
            for (int r = 0; r < 4; ++r) {
                const int bb = brow + wm * 128 + mf * 16 + lk * 4 + r;
                const size_t idx2 = (size_t)bb * H_SZ + h;
                float it = acc[mf][0][r] + vbi;
                float ft = acc[mf][1][r] + vbf;
                float ot = acc[mf][2][r] + vbo;
                float zt = acc[mf][3][r] + vbz;
                it = fminf(fmaxf(it, -50.f), 50.f);
                ft = fminf(fmaxf(ft, -50.f), 50.f);
                ot = fminf(fmaxf(ot, -50.f), 50.f);
                zt = fminf(fmaxf(zt, -50.f), 50.f);
                float f_sig = fsigmoid(ft);
                f_sig = fminf(fmaxf(f_sig, EPSF), 1.0f - EPSF);
                const float log_f = __logf(f_sig);
                const float li  = (it > -6.9f) ? it : __logf(__expf(it) + EPSF);
                const float m_t = fmaxf(log_f, li);
                const float i_pr = __expf(it - m_t);
                const float c_t  = i_pr * ftanh(zt);
                const float n_t  = i_pr;
                const float c_hat = c_t * frcp(n_t + EPSF);
                const float h_t   = fsigmoid(ot) * ftanh(c_hat);
                out[idx2]                 = h_t;
                out[idx2 + OUTSTRIDE]     = h_t;
                out[idx2 + 2 * OUTSTRIDE] = c_t;
                out[idx2 + 3 * OUTSTRIDE] = n_t;
                out[idx2 + 4 * OUTSTRIDE] = m_t;
            }
        }
    } else {
#pragma unroll
        for (int mf = 0; mf < 8; ++mf) {
#pragma unroll
            for (int r = 0; r < 4; ++r) {
                const int bb = brow + wm * 128 + mf * 16 + lk * 4 + r;
                const size_t idx2 = (size_t)bb * H_SZ + h;
                float it = acc[mf][0][r] + vbi;
                float ft = acc[mf][1][r] + vbf;
                float ot = acc[mf][2][r] + vbo;
                float zt = acc[mf][3][r] + vbz;
                it = fminf(fmaxf(it, -50.f), 50.f);
                ft = fminf(fmaxf(ft, -50.f), 50.f);
                ot = fminf(fmaxf(ot, -50.f), 50.f);
                zt = fminf(fmaxf(zt, -50.f), 50.f);
                float f_sig = fsigmoid(ft);
                f_sig = fminf(fmaxf(f_sig, EPSF), 1.0f - EPSF);
                const float log_f = __logf(f_sig);
                const float li  = (it > -6.9f) ? it : __logf(__expf(it) + EPSF);
                const float mp  = m_prev[idx2];
                const float m_t = fmaxf(log_f + mp, li);
                const float i_pr = __expf(it - m_t);
                const float f_pr = __expf(log_f + mp - m_t);
                const float c_t  = f_pr * c_prev[idx2] + i_pr * ftanh(zt);
                const float n_t  = f_pr * n_prev[idx2] + i_pr;
                const float c_hat = c_t * frcp(n_t + EPSF);
                const float h_t   = fsigmoid(ot) * ftanh(c_hat);
                out[idx2]                 = h_t;
                out[idx2 + OUTSTRIDE]     = h_t;
                out[idx2 + 2 * OUTSTRIDE] = c_t;
                out[idx2 + 3 * OUTSTRIDE] = n_t;
                out[idx2 + 4 * OUTSTRIDE] = m_t;
            }
        }
    }
}

extern "C" void kernel_launch(void* const* d_in, const int* in_sizes, int n_in,
                              void* d_out, int out_size, void* d_ws, size_t ws_size,
                              hipStream_t stream) {
    const float* x   = (const float*)d_in[0];
    const float* hp  = (const float*)d_in[1];
    const float* cp  = (const float*)d_in[2];
    const float* np_ = (const float*)d_in[3];
    const float* mp  = (const float*)d_in[4];
    const float* w_i = (const float*)d_in[5];
    const float* r_i = (const float*)d_in[6];
    const float* b_i = (const float*)d_in[7];
    const float* w_f = (const float*)d_in[8];
    const float* r_f = (const float*)d_in[9];
    const float* b_f = (const float*)d_in[10];
    const float* w_o = (const float*)d_in[11];
    const float* r_o = (const float*)d_in[12];
    const float* b_o = (const float*)d_in[13];
    const float* w_z = (const float*)d_in[14];
    const float* r_z = (const float*)d_in[15];
    const float* b_z = (const float*)d_in[16];

    ushort* XH = (ushort*)d_ws;                       // 32 MB
    ushort* Wp = XH + (size_t)B_SZ * K_SZ;            // 16 MB
    int* flags = (ws_size >= (size_t)FLAG_OFF + 2 * sizeof(int))
                     ? (int*)((char*)d_ws + FLAG_OFF) : nullptr;

    if (flags) hipMemsetAsync(flags, 0, 2 * sizeof(int), stream);
    prologue_main<<<2048, 256, 0, stream>>>(x, hp, cp, np_, mp,
                                            w_i, w_f, w_o, w_z, XH, Wp, flags);
    pack_hr<<<6144, 256, 0, stream>>>(hp, r_i, r_f, r_o, r_z, XH, Wp, flags);
    slstm_fused<<<512, 512, 0, stream>>>(
        XH, Wp, cp, np_, mp, b_i, b_f, b_o, b_z, flags, (float*)d_out);
}

// Round 16
// 129.472 us; speedup vs baseline: 1.1046x; 1.1046x over previous
//
#include <hip/hip_runtime.h>
#include <hip/hip_bf16.h>

// sLSTM cell: B=8192, I=1024, H=1024.
// G = [x|h] @ [W|R]^T  (M=8192, N=4096=4 gates x 1024, K=2048), then elementwise.
// Round 16: pure revert to round-14 (session best, 129.9us). Round-15's NT
// A-staging regressed (A was benefiting from paired-CU L2 second-touch).
// Final accounting: prologue 32us (HBM BW floor) + GEMM 72us (41 skeleton at
// 71% MfmaUtil + 31 L3-path staging tax, 9 levers exhausted) + epilogue 26us
// (HBM write floor).

#define B_SZ 8192
#define K_SZ 2048
#define H_SZ 1024
#define OUTSTRIDE 8388608   // B_SZ*H_SZ
#define EPSF 1e-7f
#define NT 32               // K_SZ / 64 (full-K trip count)
#define ATILE 16384         // ushorts per A K-tile buffer (256 rows x 64 k)
#define BTILE 16384
#define FLAG_OFF (48u * 1024u * 1024u)   // flags location in d_ws (bytes)

using bf16x8 = __attribute__((ext_vector_type(8))) short;
using f32x4  = __attribute__((ext_vector_type(4))) float;

__device__ inline ushort f2bf(float f) {
    uint u = __float_as_uint(f);
    u = (u + 0x7fffu + ((u >> 16) & 1u)) >> 16;
    return (ushort)u;
}

#if __has_builtin(__builtin_amdgcn_rcpf)
__device__ inline float frcp(float x) { return __builtin_amdgcn_rcpf(x); }
#else
__device__ inline float frcp(float x) { return 1.0f / x; }
#endif
__device__ inline float fsigmoid(float x) { return frcp(1.0f + __expf(-x)); }
__device__ inline float ftanh(float x) {
    return 1.0f - 2.0f * frcp(__expf(2.0f * x) + 1.0f);
}

#define GLOAD16(gp, lp)                                                              \
    __builtin_amdgcn_global_load_lds((const __attribute__((address_space(1))) void*)(gp), \
                                     (__attribute__((address_space(3))) void*)(lp),  \
                                     16, 0, 0)

#define BAR() do { asm volatile("" ::: "memory"); __builtin_amdgcn_s_barrier(); \
                   asm volatile("" ::: "memory"); } while (0)
#define WAITVM(n) asm volatile("s_waitcnt vmcnt(" #n ")" ::: "memory")

// pack one 8-float chunk -> 8 bf16 (uint4)
__device__ inline void pack_chunk(const float* __restrict__ src, ushort* __restrict__ dst) {
    float4 v0 = ((const float4*)src)[0];
    float4 v1 = ((const float4*)src)[1];
    uint4 o;
    o.x = (uint)f2bf(v0.x) | ((uint)f2bf(v0.y) << 16);
    o.y = (uint)f2bf(v0.z) | ((uint)f2bf(v0.w) << 16);
    o.z = (uint)f2bf(v1.x) | ((uint)f2bf(v1.y) << 16);
    o.w = (uint)f2bf(v1.z) | ((uint)f2bf(v1.w) << 16);
    ((uint4*)dst)[0] = o;
}

// ---------------- consolidated prologue ----------------

__global__ __launch_bounds__(256)
void prologue_main(const float* __restrict__ x, const float* __restrict__ h,
                   const float* __restrict__ c, const float* __restrict__ n,
                   const float* __restrict__ m,
                   const float* __restrict__ w_i, const float* __restrict__ w_f,
                   const float* __restrict__ w_o, const float* __restrict__ w_z,
                   ushort* __restrict__ XH, ushort* __restrict__ Wp,
                   int* __restrict__ flags) {
    const int gid = blockIdx.x * 256 + threadIdx.x;   // [0, 524288)
    const int NTHR = 2048 * 256;

    // x-half pack: chunk j -> row j>>7, kc j&127 (2 iters/thread)
#pragma unroll
    for (int it = 0; it < 2; ++it) {
        const int j = gid + it * NTHR;
        const int b = j >> 7, kc = j & 127;
        pack_chunk(x + (size_t)b * 1024 + kc * 8, XH + (size_t)b * 2048 + kc * 8);
    }
    // W-half pack: 1 chunk/thread
    {
        const int nn = gid >> 7, kc = gid & 127;
        const int g = nn >> 10, hr = nn & 1023;
        const float* wsel = (g == 0) ? w_i : (g == 1) ? w_f : (g == 2) ? w_o : w_z;
        pack_chunk(wsel + (size_t)hr * 1024 + kc * 8, Wp + (size_t)nn * 2048 + kc * 8);
    }
    // detection (NT loads; these arrays are read-once before the fused kernel)
    if (flags) {
        const int NF4 = (B_SZ * H_SZ) / 4;   // 2097152
        const f32x4* h4 = (const f32x4*)h;
        const f32x4* c4 = (const f32x4*)c;
        const f32x4* n4 = (const f32x4*)n;
        const f32x4* m4 = (const f32x4*)m;
        bool nzh = false, nzc = false;
        for (int i = gid; i < NF4; i += NTHR) {
            f32x4 vh = __builtin_nontemporal_load(h4 + i);
            nzh |= (vh[0] != 0.f) | (vh[1] != 0.f) | (vh[2] != 0.f) | (vh[3] != 0.f);
            f32x4 vc = __builtin_nontemporal_load(c4 + i);
            f32x4 vn = __builtin_nontemporal_load(n4 + i);
            f32x4 vm = __builtin_nontemporal_load(m4 + i);
            nzc |= (vc[0] != 0.f) | (vc[1] != 0.f) | (vc[2] != 0.f) | (vc[3] != 0.f);
            nzc |= (vn[0] != 0.f) | (vn[1] != 0.f) | (vn[2] != 0.f) | (vn[3] != 0.f);
            nzc |= (vm[0] != 0.f) | (vm[1] != 0.f) | (vm[2] != 0.f) | (vm[3] != 0.f);
        }
        if (__ballot(nzh) != 0ull && (threadIdx.x & 63) == 0) atomicOr(flags, 1);
        if (__ballot(nzc) != 0ull && (threadIdx.x & 63) == 0) atomicOr(flags + 1, 1);
    }
}

// h-half of XH + R-half of Wp; skipped when h==0 (fused never reads k>=1024 at nt=16)
__global__ __launch_bounds__(256)
void pack_hr(const float* __restrict__ h,
             const float* __restrict__ r_i, const float* __restrict__ r_f,
             const float* __restrict__ r_o, const float* __restrict__ r_z,
             ushort* __restrict__ XH, ushort* __restrict__ Wp,
             const int* __restrict__ flags) {
    if (flags && flags[0] == 0) return;
    const int gid = blockIdx.x * 256 + threadIdx.x;   // [0, 1572864)
    if (gid < 1048576) {
        const int b = gid >> 7, kc = gid & 127;
        pack_chunk(h + (size_t)b * 1024 + kc * 8,
                   XH + (size_t)b * 2048 + 1024 + kc * 8);
    } else {
        const int j = gid - 1048576;
        const int nn = j >> 7, kc = j & 127;
        const int g = nn >> 10, hr = nn & 1023;
        const float* rsel = (g == 0) ? r_i : (g == 1) ? r_f : (g == 2) ? r_o : r_z;
        pack_chunk(rsel + (size_t)hr * 1024 + kc * 8,
                   Wp + (size_t)nn * 2048 + 1024 + kc * 8);
    }
}

// ---------------- fused GEMM + sLSTM epilogue (r12 body, plain stores) ----------------

__global__ __launch_bounds__(512, 2)
void slstm_fused(const ushort* __restrict__ XH, const ushort* __restrict__ Wp,
                 const float* __restrict__ c_prev, const float* __restrict__ n_prev,
                 const float* __restrict__ m_prev,
                 const float* __restrict__ bi_, const float* __restrict__ bf_,
                 const float* __restrict__ bo_, const float* __restrict__ bz_,
                 const int* __restrict__ flags,
                 float* __restrict__ out) {
    __shared__ __align__(16) ushort Alds[3 * ATILE];   // 96 KB (triple)
    __shared__ __align__(16) ushort Blds[2 * BTILE];   // 64 KB (double)

    const int nt = (flags == nullptr) ? NT : (flags[0] ? NT : NT / 2);
    const bool cz = (flags != nullptr) && (flags[1] == 0);   // c/n/m all zero

    const int tid  = threadIdx.x;
    const int lane = tid & 63;
    const int wave = tid >> 6;
    const int wm = wave >> 2, wn = wave & 3;   // 2 x 4 waves
    const int l16 = lane & 15, lk = lane >> 4;

    // XCD-pairing swizzle
    const int wgid  = blockIdx.x;
    const int xcd   = wgid & 7;
    const int rr    = (wgid >> 3) & 31;
    const int rnd   = wgid >> 8;
    const int hcol  = (2 * xcd + (rr & 1)) * 64;
    const int brow  = (16 * rnd + (rr >> 1)) * 256;

    // per-lane pre-swizzled staging source pointers
    const ushort* srcA[4];
    const ushort* srcB[4];
#pragma unroll
    for (int c = 0; c < 4; ++c) {
        const int s = c * 512 + tid;          // linear 16B slot
        const int row = s >> 3, cph = s & 7;
        const int cl = cph ^ (row & 7);       // logical chunk
        srcA[c] = XH + (size_t)(brow + row) * 2048 + cl * 8;
        const int g = row >> 6, hh = row & 63;
        srcB[c] = Wp + (size_t)(g * 1024 + hcol + hh) * 2048 + cl * 8;
    }

    const int x7  = l16 & 7;
    const int cA0 = ((0 + lk) ^ x7) * 8;      // kh=0 phys chunk
    const int cA1 = ((4 + lk) ^ x7) * 8;      // kh=1 phys chunk
    const int abase = (wm * 128 + l16) * 64;
    const int bbase = (wn * 16 + l16) * 64;

    f32x4 acc[8][4];                          // [mf][gate]
#pragma unroll
    for (int m = 0; m < 8; ++m)
#pragma unroll
        for (int g = 0; g < 4; ++g)
            acc[m][g] = (f32x4){0.f, 0.f, 0.f, 0.f};

#define STAGE(srcarr, ldsbase, tko)                                      \
    do {                                                                 \
        _Pragma("unroll")                                                \
        for (int c = 0; c < 4; ++c)                                      \
            GLOAD16(srcarr[c] + (tko), (ldsbase) + (c * 512 + wave * 64) * 8); \
    } while (0)

    const ushort* Acur = Alds;
    const ushort* Anext = Alds + ATILE;
    const ushort* Athird = Alds + 2 * ATILE;

    // prologue: B(0),A(0),B(1),A(1),A(2); WAITVM(12) retires B(0),A(0)
    STAGE(srcB, Blds, 0);
    STAGE(srcA, (ushort*)Acur, 0);
    STAGE(srcB, Blds + BTILE, 64);
    STAGE(srcA, (ushort*)Anext, 64);
    STAGE(srcA, (ushort*)Athird, 128);
    WAITVM(12);
    BAR();

    bf16x8 a_lo[4][2], a_hi[4][2], b01[2][2], b23[2][2];

#pragma unroll
    for (int m = 0; m < 4; ++m) {
        a_lo[m][0] = *(const bf16x8*)(Acur + abase + m * 1024 + cA0);
        a_lo[m][1] = *(const bf16x8*)(Acur + abase + m * 1024 + cA1);
    }
#pragma unroll
    for (int g = 0; g < 2; ++g) {
        b01[g][0] = *(const bf16x8*)(Blds + bbase + g * 4096 + cA0);
        b01[g][1] = *(const bf16x8*)(Blds + bbase + g * 4096 + cA1);
    }

    for (int t = 0; t < nt; ++t) {
        const ushort* Bb = Blds + (t & 1) * BTILE;
        ushort* Bw = (ushort*)Bb;             // B(t+2) dest (same parity)
        ushort* Aw = (ushort*)Acur;           // A(t+3) dest = buf t%3
        const bool stB = (t < nt - 2);
        const bool stA = (t < nt - 3);

        // ---- P0: issue b23(t) reads; MFMA mf0-3 x g0-1 ----
#pragma unroll
        for (int g = 0; g < 2; ++g) {
            b23[g][0] = *(const bf16x8*)(Bb + bbase + (g + 2) * 4096 + cA0);
            b23[g][1] = *(const bf16x8*)(Bb + bbase + (g + 2) * 4096 + cA1);
        }
        __builtin_amdgcn_s_setprio(1);
#pragma unroll
        for (int m = 0; m < 4; ++m)
#pragma unroll
            for (int g = 0; g < 2; ++g) {
                acc[m][g] = __builtin_amdgcn_mfma_f32_16x16x32_bf16(a_lo[m][0], b01[g][0], acc[m][g], 0, 0, 0);
                acc[m][g] = __builtin_amdgcn_mfma_f32_16x16x32_bf16(a_lo[m][1], b01[g][1], acc[m][g], 0, 0, 0);
            }
        __builtin_amdgcn_s_setprio(0);

        // ---- P1: issue a_hi(t) reads; MFMA mf0-3 x g2-3; BAR_a ----
#pragma unroll
        for (int m = 0; m < 4; ++m) {
            a_hi[m][0] = *(const bf16x8*)(Acur + abase + (m + 4) * 1024 + cA0);
            a_hi[m][1] = *(const bf16x8*)(Acur + abase + (m + 4) * 1024 + cA1);
        }
        __builtin_amdgcn_s_setprio(1);
#pragma unroll
        for (int m = 0; m < 4; ++m)
#pragma unroll
            for (int g = 0; g < 2; ++g) {
                acc[m][g + 2] = __builtin_amdgcn_mfma_f32_16x16x32_bf16(a_lo[m][0], b23[g][0], acc[m][g + 2], 0, 0, 0);
                acc[m][g + 2] = __builtin_amdgcn_mfma_f32_16x16x32_bf16(a_lo[m][1], b23[g][1], acc[m][g + 2], 0, 0, 0);
            }
        __builtin_amdgcn_s_setprio(0);
        BAR();   // BAR_a: all B(t) reads complete -> B stage may begin

        // ---- P2: stage B(t+2); MFMA mf4-7 x g0-1; BAR_b ----
        if (stB) STAGE(srcB, Bw, (t + 2) * 64);
        __builtin_amdgcn_s_setprio(1);
#pragma unroll
        for (int m = 0; m < 4; ++m)
#pragma unroll
            for (int g = 0; g < 2; ++g) {
                acc[m + 4][g] = __builtin_amdgcn_mfma_f32_16x16x32_bf16(a_hi[m][0], b01[g][0], acc[m + 4][g], 0, 0, 0);
                acc[m + 4][g] = __builtin_amdgcn_mfma_f32_16x16x32_bf16(a_hi[m][1], b01[g][1], acc[m + 4][g], 0, 0, 0);
            }
        __builtin_amdgcn_s_setprio(0);
        BAR();   // BAR_b: all A(t) reads complete -> A stage may begin

        // ---- P3: stage A(t+3); MFMA mf4-7 x g2-3; WAITVM; BAR_c ----
        if (stA) STAGE(srcA, Aw, (t + 3) * 64);
        __builtin_amdgcn_s_setprio(1);
#pragma unroll
        for (int m = 0; m < 4; ++m)
#pragma unroll
            for (int g = 0; g < 2; ++g) {
                acc[m + 4][g + 2] = __builtin_amdgcn_mfma_f32_16x16x32_bf16(a_hi[m][0], b23[g][0], acc[m + 4][g + 2], 0, 0, 0);
                acc[m + 4][g + 2] = __builtin_amdgcn_mfma_f32_16x16x32_bf16(a_hi[m][1], b23[g][1], acc[m + 4][g + 2], 0, 0, 0);
            }
        __builtin_amdgcn_s_setprio(0);
        if (t < nt - 3) { WAITVM(12); } else { WAITVM(0); }
        BAR();   // BAR_c

        // ---- next-tile frag reads ----
        if (t < nt - 1) {
            const ushort* Bn = Blds + ((t + 1) & 1) * BTILE;
#pragma unroll
            for (int m = 0; m < 4; ++m) {
                a_lo[m][0] = *(const bf16x8*)(Anext + abase + m * 1024 + cA0);
                a_lo[m][1] = *(const bf16x8*)(Anext + abase + m * 1024 + cA1);
            }
#pragma unroll
            for (int g = 0; g < 2; ++g) {
                b01[g][0] = *(const bf16x8*)(Bn + bbase + g * 4096 + cA0);
                b01[g][1] = *(const bf16x8*)(Bn + bbase + g * 4096 + cA1);
            }
        }
        // rotate A buffers
        const ushort* tmp = Acur;
        Acur = Anext; Anext = Athird; Athird = tmp;
    }
#undef STAGE

    // ---- in-register sLSTM epilogue (fast-math, plain stores) ----
    const int h = hcol + wn * 16 + l16;
    const float vbi = bi_[h], vbf = bf_[h], vbo = bo_[h], vbz = bz_[h];

    if (cz) {
        // zero-state path: bit-identical to full path with c=n=m=0
#pragma unroll
        for (int mf = 0; mf < 8; ++mf) {
#pragma unroll
            for (int r = 0; r < 4; ++r) {
                const int bb = brow + wm * 128 + mf * 16 + lk * 4 + r;
                const size_t idx2 = (size_t)bb * H_SZ + h;
                float it = acc[mf][0][r] + vbi;
                float ft = acc[mf][1][r] + vbf;
                float ot = acc[mf][2][r] + vbo;
                float zt = acc[mf][3][r] + vbz;
                it = fminf(fmaxf(it, -50.f), 50.f);
                ft = fminf(fmaxf(ft, -50.f), 50.f);
                ot = fminf(fmaxf(ot, -50.f), 50.f);
                zt = fminf(fmaxf(zt, -50.f), 50.f);
                float f_sig = fsigmoid(ft);
                f_sig = fminf(fmaxf(f_sig, EPSF), 1.0f - EPSF);
                const float log_f = __logf(f_sig);
                const float li  = (it > -6.9f) ? it : __logf(__expf(it) + EPSF);
                const float m_t = fmaxf(log_f, li);
                const float i_pr = __expf(it - m_t);
                const float c_t  = i_pr * ftanh(zt);
                const float n_t  = i_pr;
                const float c_hat = c_t * frcp(n_t + EPSF);
                const float h_t   = fsigmoid(ot) * ftanh(c_hat);
                out[idx2]                 = h_t;
                out[idx2 + OUTSTRIDE]     = h_t;
                out[idx2 + 2 * OUTSTRIDE] = c_t;
                out[idx2 + 3 * OUTSTRIDE] = n_t;
                out[idx2 + 4 * OUTSTRIDE] = m_t;
            }
        }
    } else {
#pragma unroll
        for (int mf = 0; mf < 8; ++mf) {
#pragma unroll
            for (int r = 0; r < 4; ++r) {
                const int bb = brow + wm * 128 + mf * 16 + lk * 4 + r;
                const size_t idx2 = (size_t)bb * H_SZ + h;
                float it = acc[mf][0][r] + vbi;
                float ft = acc[mf][1][r] + vbf;
                float ot = acc[mf][2][r] + vbo;
                float zt = acc[mf][3][r] + vbz;
                it = fminf(fmaxf(it, -50.f), 50.f);
                ft = fminf(fmaxf(ft, -50.f), 50.f);
                ot = fminf(fmaxf(ot, -50.f), 50.f);
                zt = fminf(fmaxf(zt, -50.f), 50.f);
                float f_sig = fsigmoid(ft);
                f_sig = fminf(fmaxf(f_sig, EPSF), 1.0f - EPSF);
                const float log_f = __logf(f_sig);
                const float li  = (it > -6.9f) ? it : __logf(__expf(it) + EPSF);
                const float mp  = m_prev[idx2];
                const float m_t = fmaxf(log_f + mp, li);
                const float i_pr = __expf(it - m_t);
                const float f_pr = __expf(log_f + mp - m_t);
                const float c_t  = f_pr * c_prev[idx2] + i_pr * ftanh(zt);
                const float n_t  = f_pr * n_prev[idx2] + i_pr;
                const float c_hat = c_t * frcp(n_t + EPSF);
                const float h_t   = fsigmoid(ot) * ftanh(c_hat);
                out[idx2]                 = h_t;
                out[idx2 + OUTSTRIDE]     = h_t;
                out[idx2 + 2 * OUTSTRIDE] = c_t;
                out[idx2 + 3 * OUTSTRIDE] = n_t;
                out[idx2 + 4 * OUTSTRIDE] = m_t;
            }
        }
    }
}

extern "C" void kernel_launch(void* const* d_in, const int* in_sizes, int n_in,
                              void* d_out, int out_size, void* d_ws, size_t ws_size,
                              hipStream_t stream) {
    const float* x   = (const float*)d_in[0];
    const float* hp  = (const float*)d_in[1];
    const float* cp  = (const float*)d_in[2];
    const float* np_ = (const float*)d_in[3];
    const float* mp  = (const float*)d_in[4];
    const float* w_i = (const float*)d_in[5];
    const float* r_i = (const float*)d_in[6];
    const float* b_i = (const float*)d_in[7];
    const float* w_f = (const float*)d_in[8];
    const float* r_f = (const float*)d_in[9];
    const float* b_f = (const float*)d_in[10];
    const float* w_o = (const float*)d_in[11];
    const float* r_o = (const float*)d_in[12];
    const float* b_o = (const float*)d_in[13];
    const float* w_z = (const float*)d_in[14];
    const float* r_z = (const float*)d_in[15];
    const float* b_z = (const float*)d_in[16];

    ushort* XH = (ushort*)d_ws;                       // 32 MB
    ushort* Wp = XH + (size_t)B_SZ * K_SZ;            // 16 MB
    int* flags = (ws_size >= (size_t)FLAG_OFF + 2 * sizeof(int))
                     ? (int*)((char*)d_ws + FLAG_OFF) : nullptr;

    if (flags) hipMemsetAsync(flags, 0, 2 * sizeof(int), stream);
    prologue_main<<<2048, 256, 0, stream>>>(x, hp, cp, np_, mp,
                                            w_i, w_f, w_o, w_z, XH, Wp, flags);
    pack_hr<<<6144, 256, 0, stream>>>(hp, r_i, r_f, r_o, r_z, XH, Wp, flags);
    slstm_fused<<<512, 512, 0, stream>>>(
        XH, Wp, cp, np_, mp, b_i, b_f, b_o, b_z, flags, (float*)d_out);
}